// Round 14
// baseline (132.168 us; speedup 1.0000x reference)
//
#include <hip/hip_runtime.h>
#include <hip/hip_bf16.h>

#define NB   32
#define DIMK 512
#define MM   32
#define ZZ   64
#define MZV  2048
#define VOC  50257
#define NK4  1571                        // (VOC+31)/32 k4-type blocks

typedef __attribute__((ext_vector_type(8))) short  short8;   // 8 bf16 = 4 VGPR
typedef __attribute__((ext_vector_type(4))) float  f32x4;
typedef __attribute__((ext_vector_type(8))) unsigned short ushort8;

// ws layout in floats
#define WS_W      0                       // [NB][MZV] raw scores (incl. log mask)
#define WS_PVEC   (WS_W + NB*MZV)         // [NB][MM][DIMK] partial weighted vecs
#define WS_LSTAT  (WS_PVEC + NB*MM*DIMK)  // [NB][MM][2] (max, sum)
#define WS_GSTATW (WS_LSTAT + NB*MM*2)    // [NB][2] global (max,sum) copy branch
#define WS_MIX    (WS_GSTATW + NB*2)      // [NB][2]
#define WS_GPART  (WS_MIX + NB*2)         // [NB][32][2] gen softmax partials

// pack 8 f32 -> 8 bf16 (RNE) via v_cvt_pk_bf16_f32 (compiler-generated)
__device__ __forceinline__ ushort8 cvt8(float4 a, float4 b) {
    union { ushort8 u; __hip_bfloat162 h[4]; } r;
    r.h[0] = __float22bfloat162_rn(make_float2(a.x, a.y));
    r.h[1] = __float22bfloat162_rn(make_float2(a.z, a.w));
    r.h[2] = __float22bfloat162_rn(make_float2(b.x, b.y));
    r.h[3] = __float22bfloat162_rn(make_float2(b.z, b.w));
    return r.u;
}

// async global -> LDS, 16B per lane (direct DMA, no VGPR round-trip)
typedef const __attribute__((address_space(1))) void* gas_t;
typedef __attribute__((address_space(3))) void*       las_t;
__device__ __forceinline__ void gload16(const void* g, void* l) {
    __builtin_amdgcn_global_load_lds((gas_t)g, (las_t)l, 16, 0, 0);
}

// Fused k1 (mem-branch attention) || k4 (gen GEMM). Block-type dispatch:
//   bid < 2048: even -> k1 (sub=bid>>1), odd -> k4 (sub=bid>>1)
//   bid >= 2048: k4 tail (sub=bid-1024); k4 total = 1571
//
// k4 v14 = counted-vmcnt pipeline (T3/T4): ALL loop VMEM is global_load_lds
// DMA (uniform 2 instr/wave/chunk: 1 W f32 + 1 A f32), 4-deep LDS ring,
// raw s_barrier + s_waitcnt vmcnt(N) with N=4 in steady state (NEVER 0 until
// the tail) -> loads stay in flight across 3 iterations instead of being
// drained at every __syncthreads like v6-v13.
// Safety (m201 pattern): issue for slot S happens only AFTER the barrier that
// confirms all waves finished reading S's old chunk (their ds_read values were
// lgkm-consumed before that barrier); readers of the new chunk are guarded by
// their own vmcnt(N)+barrier.
__global__ __launch_bounds__(256, 5) void k14_fused(
    const float* __restrict__ enc, const float* __restrict__ embsumm,
    const float* __restrict__ encsumm,
    const float* __restrict__ memencs, const float* __restrict__ memembsumm,
    const float* __restrict__ memmask,
    const float* __restrict__ W_out, const float* __restrict__ b_out,
    const float* __restrict__ unk, float* __restrict__ out,
    float* __restrict__ ws)
{
    __shared__ __align__(16) union {
        struct { float sacc[4][DIMK]; float sst[4][2]; } s1;   // 8.03 KB
        struct { float w[4][1024]; float a[4][1024]; } s4;     // 16 + 16 KB ring
    } smem;

    int bid = blockIdx.x;
    int tid = threadIdx.x, wid = tid >> 6, lane = tid & 63;
    bool isK1; int sub;
    if (bid < 2048) { isK1 = ((bid & 1) == 0); sub = bid >> 1; }
    else            { isK1 = false;            sub = bid - 1024; }

    if (isK1) {
        // ================= k1: per (b,m) scores + online-softmax weighted sum =====
        int b = sub >> 5, m = sub & 31;
        int c0 = lane * 4, c1 = c0 + 256;
        const float* encb = enc + b * DIMK;
        const float* embb = embsumm + b * DIMK;
        float4 qe0 = *(const float4*)(encb + c0);
        float4 qe1 = *(const float4*)(encb + c1);
        float4 qm0 = *(const float4*)(embb + c0);
        float4 qm1 = *(const float4*)(embb + c1);
        const float* meb = memencs    + (long)(b*MM + m) * ZZ * DIMK;
        const float* mmb = memembsumm + (long)(b*MM + m) * ZZ * DIMK;
        const float* mkb = memmask    + (long)(b*MM + m) * ZZ;
        float* w_ws = ws + WS_W + b*MZV + m*ZZ;

        float lmax = -3.0e38f, lsum = 0.f;
        float4 a0 = make_float4(0.f,0.f,0.f,0.f), a1 = make_float4(0.f,0.f,0.f,0.f);

        for (int z = wid; z < ZZ; z += 4) {
            const float* mer = meb + z*DIMK;
            const float* mmr = mmb + z*DIMK;
            float4 e0 = *(const float4*)(mer + c0);
            float4 e1 = *(const float4*)(mer + c1);
            float4 s0 = *(const float4*)(mmr + c0);
            float4 s1 = *(const float4*)(mmr + c1);
            float d = e0.x*qe0.x + e0.y*qe0.y + e0.z*qe0.z + e0.w*qe0.w
                    + e1.x*qe1.x + e1.y*qe1.y + e1.z*qe1.z + e1.w*qe1.w
                    + s0.x*qm0.x + s0.y*qm0.y + s0.z*qm0.z + s0.w*qm0.w
                    + s1.x*qm1.x + s1.y*qm1.y + s1.z*qm1.z + s1.w*qm1.w;
            #pragma unroll
            for (int off = 32; off; off >>= 1) d += __shfl_xor(d, off);
            d += logf(mkb[z]);                 // mask=1 -> +0; mask=0 -> -inf
            if (lane == 0) w_ws[z] = d;
            float nm = fmaxf(lmax, d);
            float sc = __expf(lmax - nm);
            float e  = __expf(d - nm);
            lsum = lsum * sc + e;
            a0.x = a0.x*sc + e*e0.x; a0.y = a0.y*sc + e*e0.y;
            a0.z = a0.z*sc + e*e0.z; a0.w = a0.w*sc + e*e0.w;
            a1.x = a1.x*sc + e*e1.x; a1.y = a1.y*sc + e*e1.y;
            a1.z = a1.z*sc + e*e1.z; a1.w = a1.w*sc + e*e1.w;
            lmax = nm;
        }

        *(float4*)&smem.s1.sacc[wid][c0] = a0;
        *(float4*)&smem.s1.sacc[wid][c1] = a1;
        if (lane == 0) { smem.s1.sst[wid][0] = lmax; smem.s1.sst[wid][1] = lsum; }
        __syncthreads();
        float bm = fmaxf(fmaxf(smem.s1.sst[0][0], smem.s1.sst[1][0]),
                         fmaxf(smem.s1.sst[2][0], smem.s1.sst[3][0]));
        float sc0 = __expf(smem.s1.sst[0][0]-bm), sc1 = __expf(smem.s1.sst[1][0]-bm);
        float sc2 = __expf(smem.s1.sst[2][0]-bm), sc3 = __expf(smem.s1.sst[3][0]-bm);
        float bs = smem.s1.sst[0][1]*sc0 + smem.s1.sst[1][1]*sc1
                 + smem.s1.sst[2][1]*sc2 + smem.s1.sst[3][1]*sc3;
        int d0 = tid * 2;
        float2 v0 = *(float2*)&smem.s1.sacc[0][d0];
        float2 v1 = *(float2*)&smem.s1.sacc[1][d0];
        float2 v2 = *(float2*)&smem.s1.sacc[2][d0];
        float2 v3 = *(float2*)&smem.s1.sacc[3][d0];
        float p0 = v0.x*sc0 + v1.x*sc1 + v2.x*sc2 + v3.x*sc3;
        float p1 = v0.y*sc0 + v1.y*sc1 + v2.y*sc2 + v3.y*sc3;
        float* pv = ws + WS_PVEC + (long)(b*MM+m)*DIMK + d0;
        pv[0] = p0; pv[1] = p1;
        if (tid == 0) { float* ls = ws + WS_LSTAT + (b*MM+m)*2; ls[0] = bm; ls[1] = bs; }
    } else {
        // ================= k4: MFMA gen-GEMM tile (32 v x 32 b), 32x 32-k chunks ==
        int wv = wid >> 1, wb = wid & 1;
        int vt = sub * 32;

        // DMA slot mapping: slot = tid (0..255); row = slot>>3 (0..31),
        // q = slot&7 (16B quarter of the row's 128B chunk-row). LDS dest is
        // LINEAR (slot*16B); the XOR swizzle q^(row&7) rides on the GLOBAL
        // source address (m173 / rule #21: same involution on the read side).
        int srow = tid >> 3, sq = tid & 7;
        int sqs = sq ^ (srow & 7);
        const float* wbase = W_out + (long)min(vt + srow, VOC-1)*1024 + sqs*4;
        int aoff = srow*DIMK + sqs*4;     // batch row srow, swizzled quarter
        int ldst = tid * 4;               // LDS float offset of this slot

#define ISSUE(ch, bf) do {                                                   \
            gload16(wbase + (ch)*32, &smem.s4.w[bf][ldst]);                  \
            const float* asp = (((ch) < 16) ? encsumm : enc) + aoff + ((ch)&15)*32; \
            gload16(asp, &smem.s4.a[bf][ldst]); } while (0)

        int lg = lane >> 4, ln = lane & 15;
        int vrow = wv*16 + ln;            // B-operand row (vocab)
        int ab   = wb*16 + ln;            // A-operand row (batch)
        // LDS read offsets (swizzle-inverted), constant across chunks:
        int wq0 = (vrow*8 + ((lg*2)     ^ (vrow & 7))) * 4;
        int wq1 = (vrow*8 + ((lg*2 + 1) ^ (vrow & 7))) * 4;
        int aq0 = (ab*8   + ((lg*2)     ^ (ab & 7)))   * 4;
        int aq1 = (ab*8   + ((lg*2 + 1) ^ (ab & 7)))   * 4;
        f32x4 acc = {0.f, 0.f, 0.f, 0.f};

        ISSUE(0, 0); ISSUE(1, 1); ISSUE(2, 2);      // 6 outstanding

        for (int c = 0; c < 32; ++c) {
            if (c <= 29)      asm volatile("s_waitcnt vmcnt(4)" ::: "memory");
            else if (c == 30) asm volatile("s_waitcnt vmcnt(2)" ::: "memory");
            else              asm volatile("s_waitcnt vmcnt(0)" ::: "memory");
            __builtin_amdgcn_s_barrier();            // all waves: chunk c landed;
                                                     // slot (c+3)&3's readers done
            if (c + 3 < 32) ISSUE(c + 3, (c + 3) & 3);
            int bf = c & 3;
            float4 b0 = *(const float4*)&smem.s4.w[bf][wq0];
            float4 b1 = *(const float4*)&smem.s4.w[bf][wq1];
            float4 a0 = *(const float4*)&smem.s4.a[bf][aq0];
            float4 a1 = *(const float4*)&smem.s4.a[bf][aq1];
            ushort8 bu = cvt8(b0, b1);
            ushort8 au = cvt8(a0, a1);
            acc = __builtin_amdgcn_mfma_f32_16x16x32_bf16(*(short8*)&au, *(short8*)&bu,
                                                          acc, 0, 0, 0);
        }
#undef ISSUE

        // epilogue: C/D layout col=lane&15, row=(lane>>4)*4+reg  (m89-verified)
        int v = vt + vrow;
        if (v < VOC) {
            float bias = b_out[v] + logf(unk[v]);
            #pragma unroll
            for (int rr = 0; rr < 4; ++rr) {
                int m = wb*16 + lg*4 + rr;
                out[(long)m*VOC + v] = acc[rr] + bias;
            }
        }
    }
}

// Fused k2 (mem combine + mixer) || k5 (gen softmax partials):
//   bid < 32  -> k2 for b=bid
//   bid >= 32 -> k5 for b=(bid-32)>>5, chunk=(bid-32)&31
__global__ __launch_bounds__(256) void k2k5(
    const float* __restrict__ encsumm, const float* __restrict__ enc,
    const float* __restrict__ W_mix, const float* __restrict__ b_mix,
    float* __restrict__ out, float* __restrict__ ws)
{
    int bid = blockIdx.x, tid = threadIdx.x;
    if (bid < 32) {
        int b = bid;
        const float* ls = ws + WS_LSTAT + b*MM*2;
        float gm = -3.0e38f;
        #pragma unroll
        for (int m = 0; m < MM; m++) gm = fmaxf(gm, ls[m*2]);
        float gs = 0.f;
        #pragma unroll
        for (int m = 0; m < MM; m++) gs += ls[m*2+1] * __expf(ls[m*2] - gm);
        if (tid == 0) { ws[WS_GSTATW + b*2] = gm; ws[WS_GSTATW + b*2 + 1] = gs; }
        float inv = 1.0f / gs;
        int d0 = tid * 2;
        float p0 = 0.f, p1 = 0.f;
        for (int m = 0; m < MM; m++) {
            float sc = __expf(ls[m*2] - gm);
            const float* pv = ws + WS_PVEC + (long)(b*MM+m)*DIMK + d0;
            p0 += pv[0]*sc; p1 += pv[1]*sc;
        }
        out[(long)NB*VOC + b*DIMK + d0]     = p0 * inv;
        out[(long)NB*VOC + b*DIMK + d0 + 1] = p1 * inv;

        if (tid < 64) {
            int l = tid;
            float m0 = 0.f, m1 = 0.f;
            #pragma unroll
            for (int p = 0; p < 4; p++) {
                int cc = l*4 + p*256;
                float4 h4 = (cc < 512) ? *(const float4*)(encsumm + b*DIMK + cc)
                                       : *(const float4*)(enc + b*DIMK + cc - 512);
                float4 w0 = *(const float4*)(W_mix + cc);
                float4 w1 = *(const float4*)(W_mix + 1024 + cc);
                m0 += h4.x*w0.x + h4.y*w0.y + h4.z*w0.z + h4.w*w0.w;
                m1 += h4.x*w1.x + h4.y*w1.y + h4.z*w1.z + h4.w*w1.w;
            }
            #pragma unroll
            for (int off = 32; off; off >>= 1) { m0 += __shfl_xor(m0, off); m1 += __shfl_xor(m1, off); }
            if (l == 0) {
                m0 += b_mix[0]; m1 += b_mix[1];
                float mx = fmaxf(m0, m1);
                float e0 = __expf(m0-mx), e1 = __expf(m1-mx);
                float s = e0 + e1;
                ws[WS_MIX + b*2] = e0/s; ws[WS_MIX + b*2 + 1] = e1/s;
            }
        }
    } else {
        int sub = bid - 32;
        int chunk = sub & 31, b = sub >> 5;
        const float* logits = out;
        const int CH = (VOC + 31) / 32;
        int v0 = chunk * CH;
        int v1 = min(VOC, v0 + CH);
        float m = -3.0e38f, s = 0.f;
        for (int v = v0 + tid; v < v1; v += 256) {
            float x = logits[(long)b*VOC + v];
            float nm = fmaxf(m, x);
            s = s*__expf(m - nm) + __expf(x - nm);
            m = nm;
        }
        #pragma unroll
        for (int off = 32; off; off >>= 1) {
            float om = __shfl_xor(m, off), os = __shfl_xor(s, off);
            float nm = fmaxf(m, om);
            s = s*__expf(m - nm) + os*__expf(om - nm);
            m = nm;
        }
        __shared__ float sm[4], ssum[4];
        int wid = tid >> 6, lane = tid & 63;
        if (lane == 0) { sm[wid] = m; ssum[wid] = s; }
        __syncthreads();
        if (tid == 0) {
            float gm = fmaxf(fmaxf(sm[0], sm[1]), fmaxf(sm[2], sm[3]));
            float gs = ssum[0]*__expf(sm[0]-gm) + ssum[1]*__expf(sm[1]-gm)
                     + ssum[2]*__expf(sm[2]-gm) + ssum[3]*__expf(sm[3]-gm);
            ws[WS_GPART + (b*32 + chunk)*2]     = gm;
            ws[WS_GPART + (b*32 + chunk)*2 + 1] = gs;
        }
    }
}

// K6: probs = mix0 * softmax(logits), in place; merges the 32 chunk partials inline
__global__ __launch_bounds__(256) void k6_final(float* __restrict__ probs, const float* __restrict__ ws)
{
    int v = blockIdx.x*256 + threadIdx.x;
    int b = blockIdx.y;
    float gm = -3.0e38f;
    #pragma unroll
    for (int i = 0; i < 32; ++i) gm = fmaxf(gm, ws[WS_GPART + (b*32+i)*2]);
    float gs = 0.f;
    #pragma unroll
    for (int i = 0; i < 32; ++i)
        gs += ws[WS_GPART + (b*32+i)*2 + 1] * __expf(ws[WS_GPART + (b*32+i)*2] - gm);
    if (v >= VOC) return;
    float mix0 = ws[WS_MIX + b*2];
    long idx = (long)b*VOC + v;
    probs[idx] = mix0 * __expf(probs[idx] - gm) / gs;
}

// K7: copy-branch scatter: probs[b, tok] += mix1*alpha
__global__ __launch_bounds__(256) void k7_scatter(const int* __restrict__ memids,
                                                  const float* __restrict__ ws,
                                                  float* __restrict__ probs)
{
    int idx = blockIdx.x*256 + threadIdx.x;   // NB*MZV = 65536
    int b = idx >> 11, mz = idx & 2047;
    float gm = ws[WS_GSTATW + b*2], gs = ws[WS_GSTATW + b*2 + 1];
    float mix1 = ws[WS_MIX + b*2 + 1];
    float alpha = __expf(ws[WS_W + b*MZV + mz] - gm) / gs;
    int tok = memids[b*MZV + mz];
    atomicAdd(&probs[(long)b*VOC + tok], mix1 * alpha);
}

extern "C" void kernel_launch(void* const* d_in, const int* in_sizes, int n_in,
                              void* d_out, int out_size, void* d_ws, size_t ws_size,
                              hipStream_t stream)
{
    const float* enc        = (const float*)d_in[0];
    const float* encsumm    = (const float*)d_in[1];
    const float* embsumm    = (const float*)d_in[2];
    const float* memencs    = (const float*)d_in[3];
    // d_in[4] = memencsumm: provably unused (zeros in both concat middles)
    const float* memembsumm = (const float*)d_in[5];
    const float* memmask    = (const float*)d_in[6];
    const int*   memids     = (const int*)d_in[7];
    const float* W_out      = (const float*)d_in[8];
    const float* b_out      = (const float*)d_in[9];
    const float* W_mix      = (const float*)d_in[10];
    const float* b_mix      = (const float*)d_in[11];
    const float* unk        = (const float*)d_in[12];
    float* out = (float*)d_out;
    float* ws  = (float*)d_ws;

    hipLaunchKernelGGL(k14_fused, dim3(1024 + NK4), dim3(256), 0, stream,
                       enc, embsumm, encsumm, memencs, memembsumm, memmask,
                       W_out, b_out, unk, out, ws);
    hipLaunchKernelGGL(k2k5, dim3(32 + 1024), dim3(256), 0, stream,
                       encsumm, enc, W_mix, b_mix, out, ws);
    hipLaunchKernelGGL(k6_final, dim3((VOC + 255)/256, NB), dim3(256), 0, stream, out, ws);
    hipLaunchKernelGGL(k7_scatter, dim3(NB*MZV/256), dim3(256), 0, stream, memids, ws, out);
}

// Round 15
// 128.204 us; speedup vs baseline: 1.0309x; 1.0309x over previous
//
#include <hip/hip_runtime.h>
#include <hip/hip_bf16.h>

#define NB   32
#define DIMK 512
#define MM   32
#define ZZ   64
#define MZV  2048
#define VOC  50257
#define NK4  1571                        // (VOC+31)/32 k4-type blocks

typedef __attribute__((ext_vector_type(8))) short  short8;   // 8 bf16 = 4 VGPR
typedef __attribute__((ext_vector_type(4))) float  f32x4;
typedef __attribute__((ext_vector_type(8))) unsigned short ushort8;

// ws layout in floats
#define WS_W      0                       // [NB][MZV] raw scores (incl. log mask)
#define WS_PVEC   (WS_W + NB*MZV)         // [NB][MM][DIMK] partial weighted vecs
#define WS_LSTAT  (WS_PVEC + NB*MM*DIMK)  // [NB][MM][2] (max, sum)
#define WS_GSTATW (WS_LSTAT + NB*MM*2)    // [NB][2] global (max,sum) copy branch
#define WS_MIX    (WS_GSTATW + NB*2)      // [NB][2]
#define WS_GPART  (WS_MIX + NB*2)         // [NB][32][2] gen softmax partials

// pack 8 f32 -> 8 bf16 (RNE) via v_cvt_pk_bf16_f32 (compiler-generated)
__device__ __forceinline__ ushort8 cvt8(float4 a, float4 b) {
    union { ushort8 u; __hip_bfloat162 h[4]; } r;
    r.h[0] = __float22bfloat162_rn(make_float2(a.x, a.y));
    r.h[1] = __float22bfloat162_rn(make_float2(a.z, a.w));
    r.h[2] = __float22bfloat162_rn(make_float2(b.x, b.y));
    r.h[3] = __float22bfloat162_rn(make_float2(b.z, b.w));
    return r.u;
}

// async global -> LDS, 16B per lane (direct DMA, no VGPR round-trip)
typedef const __attribute__((address_space(1))) void* gas_t;
typedef __attribute__((address_space(3))) void*       las_t;
__device__ __forceinline__ void gload16(const void* g, void* l) {
    __builtin_amdgcn_global_load_lds((gas_t)g, (las_t)l, 16, 0, 0);
}

// Fused k1 (mem-branch attention) || k4 (gen GEMM). Block-type dispatch:
//   bid < 2048: even -> k1 (sub=bid>>1), odd -> k4 (sub=bid>>1)
//   bid >= 2048: k4 tail (sub=bid-1024); k4 total = 1571
// [REVERT to round-13 config: best measured 129.1 µs. The k4-path is at its
// schedule-invariant floor (8 variants, all 62±4 µs); v14's counted-vmcnt
// regressed via 2x bank conflicts + lower occupancy.]
__global__ __launch_bounds__(256, 6) void k14_fused(
    const float* __restrict__ enc, const float* __restrict__ embsumm,
    const float* __restrict__ encsumm,
    const float* __restrict__ memencs, const float* __restrict__ memembsumm,
    const float* __restrict__ memmask,
    const float* __restrict__ W_out, const float* __restrict__ b_out,
    const float* __restrict__ unk, float* __restrict__ out,
    float* __restrict__ ws)
{
    __shared__ __align__(16) union {
        struct { float sacc[4][DIMK]; float sst[4][2]; } s1;         // 8.03 KB
        struct { float w[2][2048]; unsigned short a[2][2048]; } s4;  // 16 + 8 KB
    } smem;

    int bid = blockIdx.x;
    int tid = threadIdx.x, wid = tid >> 6, lane = tid & 63;
    bool isK1; int sub;
    if (bid < 2048) { isK1 = ((bid & 1) == 0); sub = bid >> 1; }
    else            { isK1 = false;            sub = bid - 1024; }

    if (isK1) {
        // ================= k1: per (b,m) scores + online-softmax weighted sum =====
        int b = sub >> 5, m = sub & 31;
        int c0 = lane * 4, c1 = c0 + 256;
        const float* encb = enc + b * DIMK;
        const float* embb = embsumm + b * DIMK;
        float4 qe0 = *(const float4*)(encb + c0);
        float4 qe1 = *(const float4*)(encb + c1);
        float4 qm0 = *(const float4*)(embb + c0);
        float4 qm1 = *(const float4*)(embb + c1);
        const float* meb = memencs    + (long)(b*MM + m) * ZZ * DIMK;
        const float* mmb = memembsumm + (long)(b*MM + m) * ZZ * DIMK;
        const float* mkb = memmask    + (long)(b*MM + m) * ZZ;
        float* w_ws = ws + WS_W + b*MZV + m*ZZ;

        float lmax = -3.0e38f, lsum = 0.f;
        float4 a0 = make_float4(0.f,0.f,0.f,0.f), a1 = make_float4(0.f,0.f,0.f,0.f);

        for (int z = wid; z < ZZ; z += 4) {
            const float* mer = meb + z*DIMK;
            const float* mmr = mmb + z*DIMK;
            float4 e0 = *(const float4*)(mer + c0);
            float4 e1 = *(const float4*)(mer + c1);
            float4 s0 = *(const float4*)(mmr + c0);
            float4 s1 = *(const float4*)(mmr + c1);
            float d = e0.x*qe0.x + e0.y*qe0.y + e0.z*qe0.z + e0.w*qe0.w
                    + e1.x*qe1.x + e1.y*qe1.y + e1.z*qe1.z + e1.w*qe1.w
                    + s0.x*qm0.x + s0.y*qm0.y + s0.z*qm0.z + s0.w*qm0.w
                    + s1.x*qm1.x + s1.y*qm1.y + s1.z*qm1.z + s1.w*qm1.w;
            #pragma unroll
            for (int off = 32; off; off >>= 1) d += __shfl_xor(d, off);
            d += logf(mkb[z]);                 // mask=1 -> +0; mask=0 -> -inf
            if (lane == 0) w_ws[z] = d;
            float nm = fmaxf(lmax, d);
            float sc = __expf(lmax - nm);
            float e  = __expf(d - nm);
            lsum = lsum * sc + e;
            a0.x = a0.x*sc + e*e0.x; a0.y = a0.y*sc + e*e0.y;
            a0.z = a0.z*sc + e*e0.z; a0.w = a0.w*sc + e*e0.w;
            a1.x = a1.x*sc + e*e1.x; a1.y = a1.y*sc + e*e1.y;
            a1.z = a1.z*sc + e*e1.z; a1.w = a1.w*sc + e*e1.w;
            lmax = nm;
        }

        *(float4*)&smem.s1.sacc[wid][c0] = a0;
        *(float4*)&smem.s1.sacc[wid][c1] = a1;
        if (lane == 0) { smem.s1.sst[wid][0] = lmax; smem.s1.sst[wid][1] = lsum; }
        __syncthreads();
        float bm = fmaxf(fmaxf(smem.s1.sst[0][0], smem.s1.sst[1][0]),
                         fmaxf(smem.s1.sst[2][0], smem.s1.sst[3][0]));
        float sc0 = __expf(smem.s1.sst[0][0]-bm), sc1 = __expf(smem.s1.sst[1][0]-bm);
        float sc2 = __expf(smem.s1.sst[2][0]-bm), sc3 = __expf(smem.s1.sst[3][0]-bm);
        float bs = smem.s1.sst[0][1]*sc0 + smem.s1.sst[1][1]*sc1
                 + smem.s1.sst[2][1]*sc2 + smem.s1.sst[3][1]*sc3;
        int d0 = tid * 2;
        float2 v0 = *(float2*)&smem.s1.sacc[0][d0];
        float2 v1 = *(float2*)&smem.s1.sacc[1][d0];
        float2 v2 = *(float2*)&smem.s1.sacc[2][d0];
        float2 v3 = *(float2*)&smem.s1.sacc[3][d0];
        float p0 = v0.x*sc0 + v1.x*sc1 + v2.x*sc2 + v3.x*sc3;
        float p1 = v0.y*sc0 + v1.y*sc1 + v2.y*sc2 + v3.y*sc3;
        float* pv = ws + WS_PVEC + (long)(b*MM+m)*DIMK + d0;
        pv[0] = p0; pv[1] = p1;
        if (tid == 0) { float* ls = ws + WS_LSTAT + (b*MM+m)*2; ls[0] = bm; ls[1] = bs; }
    } else {
        // ================= k4: MFMA gen-GEMM tile (32 v x 32 b) ===================
        int wv = wid >> 1, wb = wid & 1;
        int vt = sub * 32;

        // W staging (DMA, source-swizzled): slot idx -> row=idx>>4, q=idx&15
        int idx0 = (wid*2 + 0)*64 + lane;
        int idx1 = (wid*2 + 1)*64 + lane;
        int wr0 = idx0 >> 4, wq0 = idx0 & 15;
        int wr1 = idx1 >> 4, wq1 = idx1 & 15;
        const float* wsrc0 = W_out + (long)min(vt + wr0, VOC-1)*1024 + ((wq0 ^ (wr0 & 7))*4);
        const float* wsrc1 = W_out + (long)min(vt + wr1, VOC-1)*1024 + ((wq1 ^ (wr1 & 7))*4);
        // A staging (reg + cvt, from L2-resident encsumm/enc): row ar, granule ag
        int ar = tid >> 3, ag = tid & 7;
        const float* hs0 = encsumm + ar*DIMK + ag*8;    // chunks 0..7
        const float* hs1 = enc     + ar*DIMK + ag*8;    // chunks 8..15
        int awpos = ar*64 + ((ag ^ (ar & 7))*8);

        int ph = sub & 15;                 // per-block k-phase rotation

#define PC(c) (((c) + ph) & 15)
#define ISSUE_W(pc, buf) do {                                         \
            gload16(wsrc0 + (pc)*64, &smem.s4.w[buf][idx0*4]);        \
            gload16(wsrc1 + (pc)*64, &smem.s4.w[buf][idx1*4]); } while (0)
#define LOADA(pc) do { const float* hp = ((pc) < 8 ? hs0 + (pc)*64 : hs1 + ((pc)-8)*64); \
            af0 = *(const float4*)(hp); af1 = *(const float4*)(hp + 4); } while (0)
#define WRITEA(buf) do { *(ushort8*)&smem.s4.a[buf][awpos] = cvt8(af0, af1); } while (0)

        int lg = lane >> 4, ln = lane & 15;
        int vrow = wv*16 + ln;            // B-operand column (vocab row)
        int ab   = wb*16 + ln;            // A-operand row (batch)
        f32x4 acc = {0.f, 0.f, 0.f, 0.f};
        float4 af0, af1;

        LOADA(PC(0)); WRITEA(0);
        LOADA(PC(1)); WRITEA(1);
        LOADA(PC(2));                      // stashed for c=0 iteration
        ISSUE_W(PC(0), 0);
        ISSUE_W(PC(1), 1);
        __syncthreads();                   // drains A writes + W DMA for 0,1

        for (int c = 0; c < 16; ++c) {
            int buf = c & 1;
            #pragma unroll
            for (int s = 0; s < 2; ++s) {
                int q = s*8 + lg*2;
                float4 b0 = *(const float4*)&smem.s4.w[buf][vrow*64 + ((q    ) ^ (vrow & 7))*4];
                float4 b1 = *(const float4*)&smem.s4.w[buf][vrow*64 + ((q + 1) ^ (vrow & 7))*4];
                int g = s*4 + lg;
                short8 afrag = *(const short8*)&smem.s4.a[buf][ab*64 + ((g ^ (ab & 7)))*8];
                ushort8 bu = cvt8(b0, b1);
                short8 bfrag = *(short8*)&bu;
                acc = __builtin_amdgcn_mfma_f32_16x16x32_bf16(afrag, bfrag, acc, 0, 0, 0);
            }
            __syncthreads();               // everyone done with buf
            if (c + 2 < 16) {
                WRITEA(buf);               // chunk PC(c+2) content (loaded last iter)
                ISSUE_W(PC(c + 2), buf);   // in flight across compute(c+1)
                if (c + 3 < 16) LOADA(PC(c + 3));
            }
        }
#undef PC
#undef ISSUE_W
#undef LOADA
#undef WRITEA

        int v = vt + vrow;
        if (v < VOC) {
            float bias = b_out[v] + logf(unk[v]);
            #pragma unroll
            for (int rr = 0; rr < 4; ++rr) {
                int m = wb*16 + lg*4 + rr;
                out[(long)m*VOC + v] = acc[rr] + bias;
            }
        }
    }
}

// Fused k2 (mem combine + mixer) || k5 (gen softmax partials):
//   bid < 32  -> k2 for b=bid
//   bid >= 32 -> k5 for b=(bid-32)>>5, chunk=(bid-32)&31
__global__ __launch_bounds__(256) void k2k5(
    const float* __restrict__ encsumm, const float* __restrict__ enc,
    const float* __restrict__ W_mix, const float* __restrict__ b_mix,
    float* __restrict__ out, float* __restrict__ ws)
{
    int bid = blockIdx.x, tid = threadIdx.x;
    if (bid < 32) {
        int b = bid;
        const float* ls = ws + WS_LSTAT + b*MM*2;
        float gm = -3.0e38f;
        #pragma unroll
        for (int m = 0; m < MM; m++) gm = fmaxf(gm, ls[m*2]);
        float gs = 0.f;
        #pragma unroll
        for (int m = 0; m < MM; m++) gs += ls[m*2+1] * __expf(ls[m*2] - gm);
        if (tid == 0) { ws[WS_GSTATW + b*2] = gm; ws[WS_GSTATW + b*2 + 1] = gs; }
        float inv = 1.0f / gs;
        int d0 = tid * 2;
        float p0 = 0.f, p1 = 0.f;
        for (int m = 0; m < MM; m++) {
            float sc = __expf(ls[m*2] - gm);
            const float* pv = ws + WS_PVEC + (long)(b*MM+m)*DIMK + d0;
            p0 += pv[0]*sc; p1 += pv[1]*sc;
        }
        out[(long)NB*VOC + b*DIMK + d0]     = p0 * inv;
        out[(long)NB*VOC + b*DIMK + d0 + 1] = p1 * inv;

        if (tid < 64) {
            int l = tid;
            float m0 = 0.f, m1 = 0.f;
            #pragma unroll
            for (int p = 0; p < 4; p++) {
                int cc = l*4 + p*256;
                float4 h4 = (cc < 512) ? *(const float4*)(encsumm + b*DIMK + cc)
                                       : *(const float4*)(enc + b*DIMK + cc - 512);
                float4 w0 = *(const float4*)(W_mix + cc);
                float4 w1 = *(const float4*)(W_mix + 1024 + cc);
                m0 += h4.x*w0.x + h4.y*w0.y + h4.z*w0.z + h4.w*w0.w;
                m1 += h4.x*w1.x + h4.y*w1.y + h4.z*w1.z + h4.w*w1.w;
            }
            #pragma unroll
            for (int off = 32; off; off >>= 1) { m0 += __shfl_xor(m0, off); m1 += __shfl_xor(m1, off); }
            if (l == 0) {
                m0 += b_mix[0]; m1 += b_mix[1];
                float mx = fmaxf(m0, m1);
                float e0 = __expf(m0-mx), e1 = __expf(m1-mx);
                float s = e0 + e1;
                ws[WS_MIX + b*2] = e0/s; ws[WS_MIX + b*2 + 1] = e1/s;
            }
        }
    } else {
        int sub = bid - 32;
        int chunk = sub & 31, b = sub >> 5;
        const float* logits = out;
        const int CH = (VOC + 31) / 32;
        int v0 = chunk * CH;
        int v1 = min(VOC, v0 + CH);
        float m = -3.0e38f, s = 0.f;
        for (int v = v0 + tid; v < v1; v += 256) {
            float x = logits[(long)b*VOC + v];
            float nm = fmaxf(m, x);
            s = s*__expf(m - nm) + __expf(x - nm);
            m = nm;
        }
        #pragma unroll
        for (int off = 32; off; off >>= 1) {
            float om = __shfl_xor(m, off), os = __shfl_xor(s, off);
            float nm = fmaxf(m, om);
            s = s*__expf(m - nm) + os*__expf(om - nm);
            m = nm;
        }
        __shared__ float sm[4], ssum[4];
        int wid = tid >> 6, lane = tid & 63;
        if (lane == 0) { sm[wid] = m; ssum[wid] = s; }
        __syncthreads();
        if (tid == 0) {
            float gm = fmaxf(fmaxf(sm[0], sm[1]), fmaxf(sm[2], sm[3]));
            float gs = ssum[0]*__expf(sm[0]-gm) + ssum[1]*__expf(sm[1]-gm)
                     + ssum[2]*__expf(sm[2]-gm) + ssum[3]*__expf(sm[3]-gm);
            ws[WS_GPART + (b*32 + chunk)*2]     = gm;
            ws[WS_GPART + (b*32 + chunk)*2 + 1] = gs;
        }
    }
}

// K6: probs = mix0 * softmax(logits), in place; merges the 32 chunk partials inline
__global__ __launch_bounds__(256) void k6_final(float* __restrict__ probs, const float* __restrict__ ws)
{
    int v = blockIdx.x*256 + threadIdx.x;
    int b = blockIdx.y;
    float gm = -3.0e38f;
    #pragma unroll
    for (int i = 0; i < 32; ++i) gm = fmaxf(gm, ws[WS_GPART + (b*32+i)*2]);
    float gs = 0.f;
    #pragma unroll
    for (int i = 0; i < 32; ++i)
        gs += ws[WS_GPART + (b*32+i)*2 + 1] * __expf(ws[WS_GPART + (b*32+i)*2] - gm);
    if (v >= VOC) return;
    float mix0 = ws[WS_MIX + b*2];
    long idx = (long)b*VOC + v;
    probs[idx] = mix0 * __expf(probs[idx] - gm) / gs;
}

// K7: copy-branch scatter: probs[b, tok] += mix1*alpha
__global__ __launch_bounds__(256) void k7_scatter(const int* __restrict__ memids,
                                                  const float* __restrict__ ws,
                                                  float* __restrict__ probs)
{
    int idx = blockIdx.x*256 + threadIdx.x;   // NB*MZV = 65536
    int b = idx >> 11, mz = idx & 2047;
    float gm = ws[WS_GSTATW + b*2], gs = ws[WS_GSTATW + b*2 + 1];
    float mix1 = ws[WS_MIX + b*2 + 1];
    float alpha = __expf(ws[WS_W + b*MZV + mz] - gm) / gs;
    int tok = memids[b*MZV + mz];
    atomicAdd(&probs[(long)b*VOC + tok], mix1 * alpha);
}

extern "C" void kernel_launch(void* const* d_in, const int* in_sizes, int n_in,
                              void* d_out, int out_size, void* d_ws, size_t ws_size,
                              hipStream_t stream)
{
    const float* enc        = (const float*)d_in[0];
    const float* encsumm    = (const float*)d_in[1];
    const float* embsumm    = (const float*)d_in[2];
    const float* memencs    = (const float*)d_in[3];
    // d_in[4] = memencsumm: provably unused (zeros in both concat middles)
    const float* memembsumm = (const float*)d_in[5];
    const float* memmask    = (const float*)d_in[6];
    const int*   memids     = (const int*)d_in[7];
    const float* W_out      = (const float*)d_in[8];
    const float* b_out      = (const float*)d_in[9];
    const float* W_mix      = (const float*)d_in[10];
    const float* b_mix      = (const float*)d_in[11];
    const float* unk        = (const float*)d_in[12];
    float* out = (float*)d_out;
    float* ws  = (float*)d_ws;

    hipLaunchKernelGGL(k14_fused, dim3(1024 + NK4), dim3(256), 0, stream,
                       enc, embsumm, encsumm, memencs, memembsumm, memmask,
                       W_out, b_out, unk, out, ws);
    hipLaunchKernelGGL(k2k5, dim3(32 + 1024), dim3(256), 0, stream,
                       encsumm, enc, W_mix, b_mix, out, ws);
    hipLaunchKernelGGL(k6_final, dim3((VOC + 255)/256, NB), dim3(256), 0, stream, out, ws);
    hipLaunchKernelGGL(k7_scatter, dim3(NB*MZV/256), dim3(256), 0, stream, memids, ws, out);
}